// Round 7
// baseline (222.982 us; speedup 1.0000x reference)
//
#include <hip/hip_runtime.h>
#include <hip/hip_bf16.h>

// Fused 3-layer tanh RNN (B=131072, T=6, V=31) + linear + tanh + softmax
// on mfma_f32_16x16x32_bf16.
//
// R7: R6 showed 2-tile interleaving bought nothing (102 vs 105 us) ->
// the wave_barrier in each layer_step is an opaque side-effecting inst
// that forces conservative lgkmcnt drains, serializing every step.
// Changes:
//  1. wave_barrier -> __atomic_signal_fence (compiler-only ordering, no
//     drain). HW DS ops execute in wave issue order, which gives the
//     cross-lane write->read ordering (same property R5/R6 relied on).
//  2. FOUR independent 16-row tiles per wave (64 rows); per tile:
//     {4 MFMA, tanh, 8 LDS writes, fence, ds_read issue} -- each tile's
//     ~120cyc read latency is covered by the next 3 tiles' compute; the
//     read's s_waitcnt sinks to its first use one layer later.
//  3. tanh = 1 - 2*rcp(exp(2x)+1): 5 ops, overflow-safe (rcp(inf)=0),
//     no clamp.
// Launch bounds stay (256,1): (256,2) caps VGPR at 128 -> catastrophic
// spill (R1/R3/R4). No-spill signature: WRITE_SIZE == 15.9 MB.

#define VD 31
#define TD 6
#define NT 4                    // independent 16-row tiles per wave
#define LROW 40                 // LDS row stride in shorts (80 B)
#define LBUF (16 * LROW)        // 640 shorts = 1280 B per buffer

typedef __attribute__((ext_vector_type(8))) short bf16x8;
typedef __attribute__((ext_vector_type(4))) float f32x4;
typedef __attribute__((ext_vector_type(4))) unsigned u32x4;
typedef float f32x4u __attribute__((ext_vector_type(4), aligned(4)));

struct raw8 { f32x4u a, b; };

__device__ __forceinline__ short f2bf(float f) {
    unsigned u = __float_as_uint(f);
    unsigned r = (u + 0x7fffu + ((u >> 16) & 1u)) >> 16;
    return (short)r;
}

// packed RNE fp32x2 -> bf16x2 (low = lo, high = hi)
__device__ __forceinline__ unsigned f2bf2u(float lo, float hi) {
    union { __hip_bfloat162 h2; unsigned u; } cvt;
    cvt.h2 = __float22bfloat162_rn(make_float2(lo, hi));
    return cvt.u;
}

// 5-op tanh: 1 - 2/(e^{2x}+1). x=+inf -> e=inf -> rcp=0 -> 1; x=-inf -> -1.
__device__ __forceinline__ float fast_tanh(float x) {
    float e = __expf(2.0f * x);
    return fmaf(-2.0f, __builtin_amdgcn_rcpf(e + 1.0f), 1.0f);
}

// raw 8-float load at fo = quad3 ? 23 : quad*8 (always in-bounds, 4B aligned)
__device__ __forceinline__ raw8 load_raw(const float* __restrict__ p, int fo) {
    raw8 r;
    r.a = *(const f32x4u*)(p + fo);
    r.b = *(const f32x4u*)(p + fo + 4);
    return r;
}

// convert raw floats to A-fragment; quad 3 shifts by one and pads k=31 with 0
__device__ __forceinline__ bf16x8 cvt_frag(raw8 r, bool q3) {
    float l[8] = {r.a[0], r.a[1], r.a[2], r.a[3], r.b[0], r.b[1], r.b[2], r.b[3]};
    float s[8];
#pragma unroll
    for (int j = 0; j < 7; ++j) s[j] = q3 ? l[j + 1] : l[j];
    s[7] = q3 ? 0.0f : l[7];
    union { u32x4 u4; bf16x8 b8; } cvt;
#pragma unroll
    for (int j = 0; j < 4; ++j) cvt.u4[j] = f2bf2u(s[2 * j], s[2 * j + 1]);
    return cvt.b8;
}

// B-fragment of W^T (B[k][n] = W[n][k]); rows n>=31 and cols k>=31 zero.
__device__ __forceinline__ bf16x8 load_wfrag(const float* __restrict__ W,
                                             int nn, int k0) {
    bf16x8 r;
#pragma unroll
    for (int j = 0; j < 8; ++j) {
        int k = k0 + j;
        float v = (nn < VD && k < VD) ? W[nn * VD + k] : 0.0f;
        r[j] = f2bf(v);
    }
    return r;
}

// compute + LDS-write phase of one tile's layer step
__device__ __forceinline__ void step_compute(
    bf16x8 ax, bf16x8 ah,
    bf16x8 wi0, bf16x8 wi1, bf16x8 wh0, bf16x8 wh1,
    float b0, float b1, short* buf, int n, int quad)
{
    f32x4 c0 = {b0, b0, b0, b0};
    f32x4 c1 = {b1, b1, b1, b1};
    c0 = __builtin_amdgcn_mfma_f32_16x16x32_bf16(ax, wi0, c0, 0, 0, 0);
    c1 = __builtin_amdgcn_mfma_f32_16x16x32_bf16(ax, wi1, c1, 0, 0, 0);
    c0 = __builtin_amdgcn_mfma_f32_16x16x32_bf16(ah, wh0, c0, 0, 0, 0);
    c1 = __builtin_amdgcn_mfma_f32_16x16x32_bf16(ah, wh1, c1, 0, 0, 0);
#pragma unroll
    for (int r = 0; r < 4; ++r) {
        unsigned u = f2bf2u(fast_tanh(c0[r]), fast_tanh(c1[r]));
        int row = quad * 4 + r;
        buf[row * LROW + n]      = (short)u;
        buf[row * LROW + 16 + n] = (short)(u >> 16);
    }
}

__device__ __forceinline__ bf16x8 step_read(const short* buf, int n, int k0) {
    return *(const bf16x8*)(buf + n * LROW + k0);
}

__global__ __launch_bounds__(256, 1) void rnn_mfma(
    const float* __restrict__ inp,   // [B, T, V]
    const float* __restrict__ h0,    // [L, B, V]
    const float* __restrict__ Wih,   // [L, V, V]
    const float* __restrict__ Whh,   // [L, V, V]
    const float* __restrict__ bih,   // [L, V]
    const float* __restrict__ bhh,   // [L, V]
    const float* __restrict__ Wlin,  // [V, V]
    const float* __restrict__ blin,  // [V]
    float* __restrict__ out,         // [B, V]
    int B)
{
    __shared__ __align__(16) short lds[4][NT][2][LBUF];   // 40 KB/block

    const int wave = threadIdx.x >> 6;
    const int lane = threadIdx.x & 63;
    const int n    = lane & 15;
    const int quad = lane >> 4;
    const int k0   = quad * 8;
    const bool q3  = (quad == 3);
    const int fo   = q3 ? 23 : k0;
    const int bbase = (blockIdx.x * 4 + wave) * (NT * 16);   // 64 rows/wave
    if (bbase >= B) return;

    // ---- stationary weight B-fragments (56 VGPRs), loaded once ----
    const float* W0 = Wih;               const float* U0 = Whh;
    const float* W1 = Wih + VD * VD;     const float* U1 = Whh + VD * VD;
    const float* W2 = Wih + 2 * VD * VD; const float* U2 = Whh + 2 * VD * VD;
    const bf16x8 wiA0 = load_wfrag(W0, n, k0),   wiA1 = load_wfrag(W0, n + 16, k0);
    const bf16x8 whA0 = load_wfrag(U0, n, k0),   whA1 = load_wfrag(U0, n + 16, k0);
    const bf16x8 wiB0 = load_wfrag(W1, n, k0),   wiB1 = load_wfrag(W1, n + 16, k0);
    const bf16x8 whB0 = load_wfrag(U1, n, k0),   whB1 = load_wfrag(U1, n + 16, k0);
    const bf16x8 wiC0 = load_wfrag(W2, n, k0),   wiC1 = load_wfrag(W2, n + 16, k0);
    const bf16x8 whC0 = load_wfrag(U2, n, k0),   whC1 = load_wfrag(U2, n + 16, k0);
    const bf16x8 wl0  = load_wfrag(Wlin, n, k0), wl1  = load_wfrag(Wlin, n + 16, k0);

    // ---- biases per lane's two N columns (pad col 31 -> 0) ----
    const bool hi_ok = (n + 16) < VD;
    const float bsA0 = bih[n] + bhh[n];
    const float bsA1 = hi_ok ? bih[n + 16] + bhh[n + 16] : 0.0f;
    const float bsB0 = bih[VD + n] + bhh[VD + n];
    const float bsB1 = hi_ok ? bih[VD + n + 16] + bhh[VD + n + 16] : 0.0f;
    const float bsC0 = bih[2 * VD + n] + bhh[2 * VD + n];
    const float bsC1 = hi_ok ? bih[2 * VD + n + 16] + bhh[2 * VD + n + 16] : 0.0f;
    const float bl0  = blin[n];
    const float bl1  = hi_ok ? blin[n + 16] : 0.0f;

    // ---- initial hidden states + x pointers, per tile ----
    bf16x8 a1[NT], a2[NT], a3[NT];
    raw8 rx[NT];
    const float* xrow[NT];
#pragma unroll
    for (int i = 0; i < NT; ++i) {
        const int row = bbase + i * 16 + n;
        a1[i] = cvt_frag(load_raw(h0 + ((size_t)0 * B + row) * VD, fo), q3);
        a2[i] = cvt_frag(load_raw(h0 + ((size_t)1 * B + row) * VD, fo), q3);
        a3[i] = cvt_frag(load_raw(h0 + ((size_t)2 * B + row) * VD, fo), q3);
        xrow[i] = inp + (size_t)row * TD * VD;
        rx[i] = load_raw(xrow[i], fo);
    }

    int p = 0;
#pragma unroll 1
    for (int t = 0; t < TD; ++t) {
        bf16x8 ax[NT];
#pragma unroll
        for (int i = 0; i < NT; ++i) ax[i] = cvt_frag(rx[i], q3);
        if (t + 1 < TD) {
#pragma unroll
            for (int i = 0; i < NT; ++i) rx[i] = load_raw(xrow[i] + (t + 1) * VD, fo);
        }
        // layer 1
#pragma unroll
        for (int i = 0; i < NT; ++i) {
            step_compute(ax[i], a1[i], wiA0, wiA1, whA0, whA1, bsA0, bsA1,
                         lds[wave][i][p], n, quad);
            __atomic_signal_fence(__ATOMIC_SEQ_CST);
            a1[i] = step_read(lds[wave][i][p], n, k0);
        }
        p ^= 1;
        // layer 2
#pragma unroll
        for (int i = 0; i < NT; ++i) {
            step_compute(a1[i], a2[i], wiB0, wiB1, whB0, whB1, bsB0, bsB1,
                         lds[wave][i][p], n, quad);
            __atomic_signal_fence(__ATOMIC_SEQ_CST);
            a2[i] = step_read(lds[wave][i][p], n, k0);
        }
        p ^= 1;
        // layer 3
#pragma unroll
        for (int i = 0; i < NT; ++i) {
            step_compute(a2[i], a3[i], wiC0, wiC1, whC0, whC1, bsC0, bsC1,
                         lds[wave][i][p], n, quad);
            __atomic_signal_fence(__ATOMIC_SEQ_CST);
            a3[i] = step_read(lds[wave][i][p], n, k0);
        }
        p ^= 1;
    }

    // ---- final linear + tanh + softmax, per tile ----
    const bool pad = (n == 15);          // col 16+15 == 31 is the pad neuron
#pragma unroll
    for (int i = 0; i < NT; ++i) {
        f32x4 c0 = {bl0, bl0, bl0, bl0};
        f32x4 c1 = {bl1, bl1, bl1, bl1};
        c0 = __builtin_amdgcn_mfma_f32_16x16x32_bf16(a3[i], wl0, c0, 0, 0, 0);
        c1 = __builtin_amdgcn_mfma_f32_16x16x32_bf16(a3[i], wl1, c1, 0, 0, 0);
#pragma unroll
        for (int r = 0; r < 4; ++r) {
            float v0 = fast_tanh(c0[r]);
            float v1 = fast_tanh(c1[r]);
            float mx = pad ? v0 : fmaxf(v0, v1);
#pragma unroll
            for (int msk = 1; msk < 16; msk <<= 1)
                mx = fmaxf(mx, __shfl_xor(mx, msk, 16));
            float e0 = __expf(v0 - mx);
            float e1 = pad ? 0.0f : __expf(v1 - mx);
            float s = e0 + e1;
#pragma unroll
            for (int msk = 1; msk < 16; msk <<= 1)
                s += __shfl_xor(s, msk, 16);
            float inv = __builtin_amdgcn_rcpf(s);
            const size_t row = (size_t)(bbase + i * 16 + quad * 4 + r);
            out[row * VD + n] = e0 * inv;
            if (!pad) out[row * VD + 16 + n] = e1 * inv;
        }
    }
}

extern "C" void kernel_launch(void* const* d_in, const int* in_sizes, int n_in,
                              void* d_out, int out_size, void* d_ws, size_t ws_size,
                              hipStream_t stream) {
    const float* inp  = (const float*)d_in[0];
    const float* h0   = (const float*)d_in[1];
    const float* Wih  = (const float*)d_in[2];
    const float* Whh  = (const float*)d_in[3];
    const float* bih  = (const float*)d_in[4];
    const float* bhh  = (const float*)d_in[5];
    const float* Wlin = (const float*)d_in[6];
    const float* blin = (const float*)d_in[7];
    float* out = (float*)d_out;

    const int B = in_sizes[0] / (TD * VD);
    const int rows_per_block = 4 * NT * 16;   // 256
    const int grid = (B + rows_per_block - 1) / rows_per_block;   // 512
    rnn_mfma<<<grid, 256, 0, stream>>>(inp, h0, Wih, Whh, bih, bhh, Wlin, blin, out, B);
}